// Round 1
// baseline (368.229 us; speedup 1.0000x reference)
//
#include <hip/hip_runtime.h>
#include <math.h>

// KANConv2D fused kernel (fp32 baseline).
// x:  (4, 32, 56, 56)
// wb: (64, 32, 3, 3)           base conv weights
// ws: (64, 288, 8)             spline weights, patch index p = c*9 + kh*3 + kw
// sc: (64,)                    spline scaler
// out:(4, 64, 56, 56) = silu(conv(x,wb)) + sc[o] * spline
//
// Grid: 196 blocks (4 batch * 7 * 7 tiles of 8x8), 512 threads (8 waves).
// Thread layout: p = tid & 63 (pixel in 8x8 tile), g = tid >> 6 (wave-uniform
// out-channel group of 8) -> weight reads are scalar (s_load broadcast).
// LDS: per channel-group of 8: [8][100][12] floats; [0..7]=bases, [8]=x value.
// Stride 12 chosen so ds_read banks (12*p10+f)%32 cover all 32 banks evenly.

#define IN_C   32
#define OUT_C  64
#define HW     56
#define TILE   8

__device__ __forceinline__ void eval_bases(float v, float bs[9]) {
    #pragma unroll
    for (int i = 0; i < 8; ++i) bs[i] = 0.0f;
    bs[8] = v;
    // knots: t_g = (g-3)*0.4 - 1, g = 0..11  (range [-2.2, 2.2))
    float t = (v + 2.2f) * 2.5f;
    if (t >= 0.0f && t < 11.0f) {
        int j = (int)t;            // 0..10 (truncation == floor for t>=0)
        if (j > 10) j = 10;
        float knot = (float)(j - 3) * 0.4f - 1.0f;
        float u  = (v - knot) * 2.5f;   // in [0,1)
        float um = 1.0f - u;
        float u2 = u * u, u3 = u2 * u;
        const float s6 = 1.0f / 6.0f;
        float w0 = um * um * um * s6;
        float w1 = (3.0f * u3 - 6.0f * u2 + 4.0f) * s6;
        float w2 = (-3.0f * u3 + 3.0f * u2 + 3.0f * u + 1.0f) * s6;
        float w3 = u3 * s6;
        int i0 = j - 3;   // basis window [i0, i0+3], clip to [0,7]
        if (i0 >= 0)              bs[i0]     = w0;
        if (i0 + 1 >= 0 && i0 < 7) bs[i0 + 1] = w1;
        if (i0 + 2 >= 0 && i0 < 6) bs[i0 + 2] = w2;
        if (i0 + 3 <= 7)          bs[i0 + 3] = w3;
    }
}

__global__ __launch_bounds__(512)
void kan_fused_kernel(const float* __restrict__ x,
                      const float* __restrict__ wb,
                      const float* __restrict__ ws,
                      const float* __restrict__ sc,
                      float* __restrict__ out) {
    // [8 channels][100 halo pixels][12: 8 bases + x + pad]
    __shared__ float lds[8 * 100 * 12];

    const int tid = threadIdx.x;
    const int bx  = blockIdx.x;            // 0..195
    const int b   = bx / 49;
    const int t   = bx - b * 49;
    const int ty  = t / 7;
    const int tx  = t - ty * 7;
    const int h0  = ty * TILE;
    const int w0  = tx * TILE;

    const int p  = tid & 63;               // pixel in 8x8 tile
    const int py = p >> 3;
    const int px = p & 7;
    const int g  = __builtin_amdgcn_readfirstlane(tid >> 6);  // 0..7, wave-uniform

    float accB[8], accS[8];
    #pragma unroll
    for (int o = 0; o < 8; ++o) { accB[o] = 0.0f; accS[o] = 0.0f; }

    for (int cg = 0; cg < 4; ++cg) {        // channel groups of 8
        __syncthreads();                    // protect LDS from previous readers
        // ---- stage: bases for 8 channels x 10x10 halo ----
        for (int i = tid; i < 800; i += 512) {
            const int c_l = i / 100;        // 0..7
            const int p10 = i - c_l * 100;
            const int hy  = p10 / 10;
            const int hx  = p10 - hy * 10;
            const int c   = cg * 8 + c_l;
            const int hh  = h0 + hy - 1;
            const int ww  = w0 + hx - 1;
            float v = 0.0f;
            if ((unsigned)hh < 56u && (unsigned)ww < 56u)
                v = x[((b * IN_C + c) * HW + hh) * HW + ww];
            float bs[9];
            eval_bases(v, bs);
            float* dst = &lds[i * 12];
            ((float4*)dst)[0] = make_float4(bs[0], bs[1], bs[2], bs[3]);
            ((float4*)dst)[1] = make_float4(bs[4], bs[5], bs[6], bs[7]);
            dst[8] = v;
        }
        __syncthreads();

        // ---- compute: 8 channels x 9 taps x 8 out-channels ----
        for (int cl = 0; cl < 8; ++cl) {
            const int c = cg * 8 + cl;
            const float* wbc = wb + (g * 8) * (IN_C * 9) + c * 9;   // + o*288 + tap
            const float* wsc = ws + (g * 8) * (288 * 8) + c * 72;   // + o*2304 + tap*8 + f
            const float* cellbase = &lds[cl * 1200 + (py * 10 + px) * 12];
            #pragma unroll
            for (int kh = 0; kh < 3; ++kh) {
                #pragma unroll
                for (int kw = 0; kw < 3; ++kw) {
                    const int tap = kh * 3 + kw;
                    const float* cell = cellbase + (kh * 10 + kw) * 12;
                    const float4 q0 = *(const float4*)cell;
                    const float4 q1 = *(const float4*)(cell + 4);
                    const float xv  = cell[8];
                    #pragma unroll
                    for (int o = 0; o < 8; ++o) {
                        accB[o] = fmaf(xv, wbc[o * (IN_C * 9) + tap], accB[o]);
                        const float* wp = wsc + o * (288 * 8) + tap * 8;
                        float s = accS[o];
                        s = fmaf(q0.x, wp[0], s);
                        s = fmaf(q0.y, wp[1], s);
                        s = fmaf(q0.z, wp[2], s);
                        s = fmaf(q0.w, wp[3], s);
                        s = fmaf(q1.x, wp[4], s);
                        s = fmaf(q1.y, wp[5], s);
                        s = fmaf(q1.z, wp[6], s);
                        s = fmaf(q1.w, wp[7], s);
                        accS[o] = s;
                    }
                }
            }
        }
    }

    // ---- epilogue: silu(base) + scaler * spline ----
    const int h = h0 + py;
    const int w = w0 + px;
    #pragma unroll
    for (int o = 0; o < 8; ++o) {
        const int oc = g * 8 + o;
        const float bval = accB[o];
        const float silu = bval / (1.0f + __expf(-bval));
        out[((b * OUT_C + oc) * HW + h) * HW + w] = silu + sc[oc] * accS[o];
    }
}

extern "C" void kernel_launch(void* const* d_in, const int* in_sizes, int n_in,
                              void* d_out, int out_size, void* d_ws, size_t ws_size,
                              hipStream_t stream) {
    const float* x  = (const float*)d_in[0];   // (4,32,56,56)
    const float* wb = (const float*)d_in[1];   // (64,32,3,3)
    const float* ws = (const float*)d_in[2];   // (64,288,8)
    const float* sc = (const float*)d_in[3];   // (64,)
    float* out = (float*)d_out;                // (4,64,56,56)

    dim3 grid(196);   // 4 batches * 7*7 tiles of 8x8
    dim3 block(512);
    kan_fused_kernel<<<grid, block, 0, stream>>>(x, wb, ws, sc, out);
}

// Round 2
// 89.534 us; speedup vs baseline: 4.1127x; 4.1127x over previous
//
#include <hip/hip_runtime.h>
#include <math.h>

// KANConv2D via bf16 MFMA (16x16x32).
// x:  (4, 32, 56, 56) fp32
// wb: (64, 32, 3, 3)  fp32 base conv weights  -> wbb bf16 [oc][p=c*9+kh*3+kw]
// ws: (64, 288, 8)    fp32 spline weights     -> wsb bf16 [oc][p][f]
// sc: (64,)           spline scaler
// out:(4, 64, 56, 56) = silu(conv(x,wb)) + sc[oc] * spline
//
// Spline GEMM: D[m][n] = sum_k A[m][k]*B[k][n], k = p*8+f (K=2304),
//   A = bases of unfolded patches, B = ws^T.
// Base GEMM:   K = 288, A = x patches, B = wb^T.
//
// Main kernel: 392 blocks = 4 batch x 14 x 7 pixel tiles of 4x8 (M=32).
// 256 threads = 4 waves; wave wv owns out-channels [wv*16, wv*16+16),
// 2 M-tiles of 16 pixels => 2 C-frags per path.
// LDS: sb[c][60][8] bf16 bases of 6x10 halo (30720 B)
//      sx[c][60]    bf16 x halo               (3840 B)
//      patch[m][288] bf16 x patches, K-layout (18432 B)   total 52992 B.

typedef __attribute__((ext_vector_type(8))) short bf16x8;
typedef __attribute__((ext_vector_type(4))) float f32x4;

#define MFMA(a, b, c) __builtin_amdgcn_mfma_f32_16x16x32_bf16((a), (b), (c), 0, 0, 0)

__device__ __forceinline__ unsigned short f2bf(float f) {
    unsigned u = __builtin_bit_cast(unsigned, f);
    u = (u + 0x7fffu + ((u >> 16) & 1u)) >> 16;   // round-to-nearest-even
    return (unsigned short)u;
}

__device__ __forceinline__ void eval_bases(float v, float bs[8]) {
    #pragma unroll
    for (int i = 0; i < 8; ++i) bs[i] = 0.0f;
    // knots: t_g = (g-3)*0.4 - 1, g = 0..11  (support [-2.2, 2.2))
    float t = (v + 2.2f) * 2.5f;
    if (t >= 0.0f && t < 11.0f) {
        int j = (int)t;
        if (j > 10) j = 10;
        float knot = (float)(j - 3) * 0.4f - 1.0f;
        float u  = (v - knot) * 2.5f;
        float um = 1.0f - u;
        float u2 = u * u, u3 = u2 * u;
        const float s6 = 1.0f / 6.0f;
        float w0 = um * um * um * s6;
        float w1 = (3.0f * u3 - 6.0f * u2 + 4.0f) * s6;
        float w2 = (-3.0f * u3 + 3.0f * u2 + 3.0f * u + 1.0f) * s6;
        float w3 = u3 * s6;
        int i0 = j - 3;
        if (i0 >= 0)               bs[i0]     = w0;
        if (i0 + 1 >= 0 && i0 < 7) bs[i0 + 1] = w1;
        if (i0 + 2 >= 0 && i0 < 6) bs[i0 + 2] = w2;
        if (i0 + 3 <= 7)           bs[i0 + 3] = w3;
    }
}

// ---- pre-kernel: fp32 weights -> bf16 ----
__global__ __launch_bounds__(256)
void cvt_weights_kernel(const float* __restrict__ ws, const float* __restrict__ wb,
                        unsigned short* __restrict__ wsb, unsigned short* __restrict__ wbb) {
    int i = blockIdx.x * 256 + threadIdx.x;
    if (i < 147456) {
        wsb[i] = f2bf(ws[i]);
    } else {
        int j = i - 147456;
        if (j < 18432) wbb[j] = f2bf(wb[j]);
    }
}

__global__ __launch_bounds__(256)
void kan_mfma_kernel(const float* __restrict__ x,
                     const float* __restrict__ sc,
                     const unsigned short* __restrict__ wsb,
                     const unsigned short* __restrict__ wbb,
                     float* __restrict__ out) {
    __shared__ unsigned short smem[26496];
    unsigned short* sb    = smem;            // 15360 ushorts
    unsigned short* sx    = smem + 15360;    // 1920
    unsigned short* patch = smem + 17280;    // 9216

    const int tid = threadIdx.x;
    const int bx  = blockIdx.x;              // 0..391
    const int b   = bx / 98;
    const int r   = bx - b * 98;
    const int ty  = r / 7;
    const int tx  = r - ty * 7;
    const int h0  = ty * 4, w0 = tx * 8;

    // ---- phase 1: bases + x for 32 channels x 6x10 halo ----
    for (int i = tid; i < 1920; i += 256) {
        int c  = i / 60;
        int hp = i - c * 60;
        int hy = hp / 10;
        int hx = hp - hy * 10;
        int hh = h0 + hy - 1, ww = w0 + hx - 1;
        float v = 0.0f;
        if ((unsigned)hh < 56u && (unsigned)ww < 56u)
            v = x[((b * 32 + c) * 56 + hh) * 56 + ww];
        float bs[8];
        eval_bases(v, bs);
        bf16x8 pk;
        #pragma unroll
        for (int j2 = 0; j2 < 8; ++j2) pk[j2] = (short)f2bf(bs[j2]);
        *reinterpret_cast<bf16x8*>(&sb[i * 8]) = pk;
        sx[i] = f2bf(v);
    }
    __syncthreads();

    // ---- phase 2: x patches in K-layout for the base GEMM ----
    {
        int m  = tid >> 3;            // 0..31
        int c0 = (tid & 7) * 4;       // 0,4,..,28
        int py = m >> 3, px = m & 7;
        const unsigned short* rsx = &sx[c0 * 60 + py * 10 + px];
        unsigned short* wp = &patch[m * 288 + c0 * 9];
        #pragma unroll
        for (int cc = 0; cc < 4; ++cc)
            #pragma unroll
            for (int kh = 0; kh < 3; ++kh)
                #pragma unroll
                for (int kw = 0; kw < 3; ++kw)
                    wp[cc * 9 + kh * 3 + kw] = rsx[cc * 60 + kh * 10 + kw];
    }
    __syncthreads();

    // ---- compute ----
    const int lane = tid & 63;
    const int wv   = tid >> 6;        // 0..3
    const int col  = lane & 15;       // A: pixel row m0; B/C: out-channel
    const int q    = lane >> 4;       // quad
    const int m0   = col;
    const int py0  = m0 >> 3, px0 = m0 & 7;
    const int oc   = wv * 16 + col;

    f32x4 accS0 = {0.f,0.f,0.f,0.f}, accS1 = {0.f,0.f,0.f,0.f};
    f32x4 accB0 = {0.f,0.f,0.f,0.f}, accB1 = {0.f,0.f,0.f,0.f};

    // per-lane A offsets: p = 36g + (4u+q); c = 4g + (4u+q)/9; tap = (4u+q)%9
    int aoff[9];
    #pragma unroll
    for (int u = 0; u < 9; ++u) {
        int t4  = 4 * u + q;          // 0..35
        int dc  = t4 / 9;
        int tap = t4 - dc * 9;
        int kh  = tap / 3;
        int kw  = tap - kh * 3;
        aoff[u] = (dc * 60 + (py0 + kh) * 10 + (px0 + kw)) * 8;   // ushort units
    }

    // spline GEMM: K = 2304 = 8 groups x 9 ksteps x 32
    const unsigned short* wBp = wsb + (oc * 288 + q) * 8;
    int gbase = 0;
    for (int g = 0; g < 8; ++g) {
        #pragma unroll
        for (int u = 0; u < 9; ++u) {
            bf16x8 a0 = *reinterpret_cast<const bf16x8*>(&sb[gbase + aoff[u]]);
            bf16x8 a1 = *reinterpret_cast<const bf16x8*>(&sb[gbase + aoff[u] + 160]); // py += 2
            bf16x8 bw = *reinterpret_cast<const bf16x8*>(wBp + g * 288 + u * 32);
            accS0 = MFMA(a0, bw, accS0);
            accS1 = MFMA(a1, bw, accS1);
        }
        gbase += 1920;
    }

    // base GEMM: K = 288 = 9 ksteps x 32
    {
        const unsigned short* ap = &patch[m0 * 288 + q * 8];
        const unsigned short* bp = wbb + oc * 288 + q * 8;
        #pragma unroll
        for (int ks = 0; ks < 9; ++ks) {
            bf16x8 a0 = *reinterpret_cast<const bf16x8*>(ap + ks * 32);
            bf16x8 a1 = *reinterpret_cast<const bf16x8*>(ap + ks * 32 + 4608);  // m += 16
            bf16x8 bw = *reinterpret_cast<const bf16x8*>(bp + ks * 32);
            accB0 = MFMA(a0, bw, accB0);
            accB1 = MFMA(a1, bw, accB1);
        }
    }

    // ---- epilogue: silu(base) + sc * spline; C-layout row = q*4+reg = pixel ----
    const float scv = sc[oc];
    float* obase = out + ((b * 64 + oc) * 56) * 56;
    #pragma unroll
    for (int mt = 0; mt < 2; ++mt) {
        f32x4 aB = mt ? accB1 : accB0;
        f32x4 aS = mt ? accS1 : accS0;
        int py  = mt * 2 + (q >> 1);
        int pxb = (q & 1) * 4;
        f32x4 res;
        #pragma unroll
        for (int reg = 0; reg < 4; ++reg) {
            float bv = aB[reg];
            float s  = bv / (1.0f + __expf(-bv));
            res[reg] = s + scv * aS[reg];
        }
        *reinterpret_cast<f32x4*>(&obase[(h0 + py) * 56 + w0 + pxb]) = res;
    }
}

extern "C" void kernel_launch(void* const* d_in, const int* in_sizes, int n_in,
                              void* d_out, int out_size, void* d_ws, size_t ws_size,
                              hipStream_t stream) {
    const float* x  = (const float*)d_in[0];   // (4,32,56,56)
    const float* wb = (const float*)d_in[1];   // (64,32,3,3)
    const float* ws = (const float*)d_in[2];   // (64,288,8)
    const float* sc = (const float*)d_in[3];   // (64,)
    float* out = (float*)d_out;                // (4,64,56,56)

    unsigned short* wsb = (unsigned short*)d_ws;        // 147456 bf16
    unsigned short* wbb = wsb + 147456;                 // 18432 bf16 (offset 294912 B)

    cvt_weights_kernel<<<648, 256, 0, stream>>>(ws, wb, wsb, wbb);
    kan_mfma_kernel<<<392, 256, 0, stream>>>(x, sc, wsb, wbb, out);
}

// Round 3
// 78.464 us; speedup vs baseline: 4.6930x; 1.1411x over previous
//
#include <hip/hip_runtime.h>
#include <math.h>

// KANConv2D via bf16 MFMA 32x32x16, R3.
// x:  (4, 32, 56, 56) fp32
// wb: (64, 32, 3, 3)  fp32 -> wbt: bf16 pre-swizzled MFMA B-frag stream
// ws: (64, 288, 8)    fp32 -> wst: bf16 pre-swizzled MFMA B-frag stream
// sc: (64,)
// out:(4, 64, 56, 56) = silu(conv(x,wb)) + sc[oc] * spline
//
// Spline GEMM: A[m=px][k=p*8+f] (bases), B[k][n=oc], K=2304 (144 k16-steps).
// Base GEMM:   A[m=px][k=c*9+tap] (x patches),      K=288  (18 k16-steps).
//
// Main: 392 blocks (4 b x 14 x 7 tiles of 4x8 px, M=32), 256 thr = 4 waves.
// Wave wv: nf = wv&1 (oc half), kh2 = wv>>1 (K half). K-split reduced via LDS.
// Frag convention (consistent for A and B, contraction-invariant):
//   lane&31 = m (A) / n (B); k = (lane>>5)*8 + j within a k16 step.
// C/D (verified m74/m101): col=lane&31=n, row=(reg&3)+8*(reg>>2)+4*(lane>>5)=m.
//
// LDS: sb[c][60][8] bf16 (30720 B), sx[c][60] (3840 B),
//      patch[32][296] bf16 (18944 B, row padded 288->296 to spread banks).

typedef __attribute__((ext_vector_type(8)))  short bf16x8;
typedef __attribute__((ext_vector_type(4)))  float f32x4;
typedef __attribute__((ext_vector_type(16))) float f32x16;

#define MFMA32(a, b, c) __builtin_amdgcn_mfma_f32_32x32x16_bf16((a), (b), (c), 0, 0, 0)

__device__ __forceinline__ unsigned short f2bf(float f) {
    unsigned u = __builtin_bit_cast(unsigned, f);
    u = (u + 0x7fffu + ((u >> 16) & 1u)) >> 16;   // RNE
    return (unsigned short)u;
}

__device__ __forceinline__ void eval_bases(float v, float bs[8]) {
    #pragma unroll
    for (int i = 0; i < 8; ++i) bs[i] = 0.0f;
    // knots: t_g = (g-3)*0.4 - 1, support [-2.2, 2.2)
    float t = (v + 2.2f) * 2.5f;
    if (t >= 0.0f && t < 11.0f) {
        int j = (int)t;
        if (j > 10) j = 10;
        float knot = (float)(j - 3) * 0.4f - 1.0f;
        float u  = (v - knot) * 2.5f;
        float um = 1.0f - u;
        float u2 = u * u, u3 = u2 * u;
        const float s6 = 1.0f / 6.0f;
        float w0 = um * um * um * s6;
        float w1 = (3.0f * u3 - 6.0f * u2 + 4.0f) * s6;
        float w2 = (-3.0f * u3 + 3.0f * u2 + 3.0f * u + 1.0f) * s6;
        float w3 = u3 * s6;
        int i0 = j - 3;
        if (i0 >= 0)               bs[i0]     = w0;
        if (i0 + 1 >= 0 && i0 < 7) bs[i0 + 1] = w1;
        if (i0 + 2 >= 0 && i0 < 6) bs[i0 + 2] = w2;
        if (i0 + 3 <= 7)           bs[i0 + 3] = w3;
    }
}

// ---- pre-kernel: fp32 weights -> bf16, pre-swizzled into MFMA B-frag order ----
// wst[t = nf*144 + s][lane][j] = ws[(nf*32 + (lane&31)) * 2304 + s*16 + (lane>>5)*8 + j]
// wbt[t = nf*18  + s][lane][j] = wb[(nf*32 + (lane&31)) * 288  + s*16 + (lane>>5)*8 + j]
__global__ __launch_bounds__(256)
void cvt_swz_kernel(const float* __restrict__ ws, const float* __restrict__ wb,
                    unsigned short* __restrict__ wst, unsigned short* __restrict__ wbt) {
    int i = blockIdx.x * 256 + threadIdx.x;
    if (i < 147456) {
        int j = i & 7, l = (i >> 3) & 63, t = i >> 9;   // t 0..287
        int s = t % 144, nf = t / 144;
        int oc = nf * 32 + (l & 31);
        int k  = s * 16 + (l >> 5) * 8 + j;
        wst[i] = f2bf(ws[oc * 2304 + k]);
    } else {
        int i2 = i - 147456;
        if (i2 < 18432) {
            int j = i2 & 7, l = (i2 >> 3) & 63, t = i2 >> 9;  // t 0..35
            int s = t % 18, nf = t / 18;
            int oc = nf * 32 + (l & 31);
            int k  = s * 16 + (l >> 5) * 8 + j;
            wbt[i2] = f2bf(wb[oc * 288 + k]);
        }
    }
}

__global__ __launch_bounds__(256)
void kan_mfma_kernel(const float* __restrict__ x,
                     const float* __restrict__ sc,
                     const unsigned short* __restrict__ wst,
                     const unsigned short* __restrict__ wbt,
                     float* __restrict__ out) {
    __shared__ unsigned short smem[26752];   // 53504 B
    unsigned short* sb    = smem;            // 15360 ushorts: [c][60][8]
    unsigned short* sx    = smem + 15360;    // 1920
    unsigned short* patch = smem + 17280;    // 9472: [32][296]

    const int tid = threadIdx.x;
    const int bx  = blockIdx.x;              // 0..391
    const int b   = bx / 98;
    const int r   = bx - b * 98;
    const int ty  = r / 7;
    const int tx  = r - ty * 7;
    const int h0  = ty * 4, w0 = tx * 8;

    // ---- phase 1: bases + x for 32 channels x 6x10 halo ----
    for (int i = tid; i < 1920; i += 256) {
        int c  = i / 60;
        int hp = i - c * 60;
        int hy = hp / 10;
        int hx = hp - hy * 10;
        int hh = h0 + hy - 1, ww = w0 + hx - 1;
        float v = 0.0f;
        if ((unsigned)hh < 56u && (unsigned)ww < 56u)
            v = x[((b * 32 + c) * 56 + hh) * 56 + ww];
        float bs[8];
        eval_bases(v, bs);
        bf16x8 pk;
        #pragma unroll
        for (int j2 = 0; j2 < 8; ++j2) pk[j2] = (short)f2bf(bs[j2]);
        *reinterpret_cast<bf16x8*>(&sb[i * 8]) = pk;
        sx[i] = f2bf(v);
    }
    __syncthreads();

    // ---- phase 2: x patches [m][k=c*9+tap], row stride 296 ----
    {
        int m2 = tid >> 3;            // 0..31
        int c0 = (tid & 7) * 4;       // 0,4,..,28
        const unsigned short* rsx = &sx[c0 * 60 + (m2 >> 3) * 10 + (m2 & 7)];
        unsigned short* wp = &patch[m2 * 296 + c0 * 9];
        #pragma unroll
        for (int cc = 0; cc < 4; ++cc)
            #pragma unroll
            for (int kh = 0; kh < 3; ++kh)
                #pragma unroll
                for (int kw = 0; kw < 3; ++kw)
                    wp[cc * 9 + kh * 3 + kw] = rsx[cc * 60 + kh * 10 + kw];
    }
    __syncthreads();

    // ---- compute ----
    const int lane = tid & 63;
    const int wv   = tid >> 6;        // 0..3
    const int nf   = wv & 1;          // oc half
    const int kh2  = wv >> 1;         // K half
    const int m    = lane & 31;       // A row = pixel
    const int kg   = lane >> 5;       // k-group within k16 step
    const int py0  = m >> 3, px0 = m & 7;

    f32x16 accS = {0.f}; f32x16 accB = {0.f};
    #pragma unroll
    for (int i = 0; i < 16; ++i) { accS[i] = 0.f; accB[i] = 0.f; }

    // spline A offsets: per k16 step s: p = 2s + kg -> c = p/9, tap = p%9.
    // s = kh2*72 + g*9 + u  =>  c = 16*kh2 + 2g + (2u+kg)/9, tap = (2u+kg)%9.
    int aoff[9];
    #pragma unroll
    for (int u = 0; u < 9; ++u) {
        int t2  = 2 * u + kg;         // 0..17
        int dc  = t2 / 9;
        int tap = t2 - dc * 9;
        int kh  = tap / 3;
        int kw  = tap - kh * 3;
        aoff[u] = (dc * 60 + (py0 + kh) * 10 + (px0 + kw)) * 8;   // ushorts
    }

    // spline GEMM: 72 k16-steps for this K-half
    const unsigned short* bp = wst + ((nf * 144 + kh2 * 72) * 64 + lane) * 8;
    int cbase = kh2 * 7680;           // (16*kh2) channels * 480 ushorts
    for (int g = 0; g < 8; ++g) {
        #pragma unroll
        for (int u = 0; u < 9; ++u) {
            bf16x8 a = *reinterpret_cast<const bf16x8*>(&sb[cbase + aoff[u]]);
            bf16x8 bw = *reinterpret_cast<const bf16x8*>(bp + (g * 9 + u) * 512);
            accS = MFMA32(a, bw, accS);
        }
        cbase += 960;
    }

    // base GEMM: 9 k16-steps for this K-half
    {
        const unsigned short* ap  = &patch[m * 296 + kg * 8];
        const unsigned short* bbp = wbt + ((nf * 18 + kh2 * 9) * 64 + lane) * 8;
        #pragma unroll
        for (int s = 0; s < 9; ++s) {
            bf16x8 a = *reinterpret_cast<const bf16x8*>(ap + (kh2 * 9 + s) * 16);
            bf16x8 bw = *reinterpret_cast<const bf16x8*>(bbp + s * 512);
            accB = MFMA32(a, bw, accB);
        }
    }

    // ---- K-split reduction: waves 2,3 pass accs to waves 0,1 via LDS ----
    __syncthreads();
    float* red = (float*)smem;        // [2][64][36] floats = 18432 B (36: bank pad)
    if (kh2 == 1) {
        float* dst = red + (nf * 64 + lane) * 36;
        #pragma unroll
        for (int rq = 0; rq < 4; ++rq) {
            f32x4 vS, vB;
            #pragma unroll
            for (int rr = 0; rr < 4; ++rr) { vS[rr] = accS[rq*4+rr]; vB[rr] = accB[rq*4+rr]; }
            *reinterpret_cast<f32x4*>(dst + rq * 4)      = vS;
            *reinterpret_cast<f32x4*>(dst + 16 + rq * 4) = vB;
        }
    }
    __syncthreads();

    if (kh2 == 0) {
        const float* src = red + (nf * 64 + lane) * 36;
        #pragma unroll
        for (int rq = 0; rq < 4; ++rq) {
            f32x4 vS = *reinterpret_cast<const f32x4*>(src + rq * 4);
            f32x4 vB = *reinterpret_cast<const f32x4*>(src + 16 + rq * 4);
            #pragma unroll
            for (int rr = 0; rr < 4; ++rr) { accS[rq*4+rr] += vS[rr]; accB[rq*4+rr] += vB[rr]; }
        }
        // ---- epilogue ----
        const int col = lane & 31;            // oc within half
        const int oc  = nf * 32 + col;
        const float scv = sc[oc];
        const int kg5 = lane >> 5;            // px sub-block
        float* ob = out + ((b * 64 + oc) * 56 + h0) * 56 + w0 + 4 * kg5;
        #pragma unroll
        for (int rq = 0; rq < 4; ++rq) {      // row = rq*8? no: py = rq
            f32x4 res;
            #pragma unroll
            for (int rr = 0; rr < 4; ++rr) {
                float bv = accB[rq * 4 + rr];
                float si = bv / (1.0f + __expf(-bv));
                res[rr] = si + scv * accS[rq * 4 + rr];
            }
            *reinterpret_cast<f32x4*>(ob + rq * 56) = res;
        }
    }
}

extern "C" void kernel_launch(void* const* d_in, const int* in_sizes, int n_in,
                              void* d_out, int out_size, void* d_ws, size_t ws_size,
                              hipStream_t stream) {
    const float* x  = (const float*)d_in[0];   // (4,32,56,56)
    const float* wb = (const float*)d_in[1];   // (64,32,3,3)
    const float* ws = (const float*)d_in[2];   // (64,288,8)
    const float* sc = (const float*)d_in[3];   // (64,)
    float* out = (float*)d_out;                // (4,64,56,56)

    unsigned short* wst = (unsigned short*)d_ws;   // 147456 bf16
    unsigned short* wbt = wst + 147456;            // 18432 bf16

    cvt_swz_kernel<<<648, 256, 0, stream>>>(ws, wb, wst, wbt);
    kan_mfma_kernel<<<392, 256, 0, stream>>>(x, sc, wst, wbt, out);
}

// Round 4
// 78.398 us; speedup vs baseline: 4.6969x; 1.0008x over previous
//
#include <hip/hip_runtime.h>
#include <math.h>

// KANConv2D via bf16 MFMA 32x32x16, R4: latency-oriented restructure.
// - LDS 49664 B (3 blocks/CU), single barrier before compute.
// - Phase 1 batches 8 independent x loads, evals bases, stores sb,
//   and scatters x (bf16) directly into the patch matrix (no sx, no phase 2).
// - Spline K-loop: ping-pong register prefetch of B frags (9 ahead) +
//   two interleaved accumulator chains (breaks MFMA dependency chain).
//
// Frag convention (A and B consistent): lane&31 = m/n; k = (lane>>5)*8 + j
// within each k16 step. C/D: col=lane&31=n, row=(reg&3)+8*(reg>>2)+4*(lane>>5).

typedef __attribute__((ext_vector_type(8)))  short bf16x8;
typedef __attribute__((ext_vector_type(4)))  float f32x4;
typedef __attribute__((ext_vector_type(16))) float f32x16;

#define MFMA32(a, b, c) __builtin_amdgcn_mfma_f32_32x32x16_bf16((a), (b), (c), 0, 0, 0)

__device__ __forceinline__ unsigned short f2bf(float f) {
    unsigned u = __builtin_bit_cast(unsigned, f);
    u = (u + 0x7fffu + ((u >> 16) & 1u)) >> 16;   // RNE
    return (unsigned short)u;
}

__device__ __forceinline__ void eval_bases(float v, float bs[8]) {
    #pragma unroll
    for (int i = 0; i < 8; ++i) bs[i] = 0.0f;
    // knots: t_g = (g-3)*0.4 - 1, support [-2.2, 2.2)
    float t = (v + 2.2f) * 2.5f;
    if (t >= 0.0f && t < 11.0f) {
        int j = (int)t;
        if (j > 10) j = 10;
        float knot = (float)(j - 3) * 0.4f - 1.0f;
        float u  = (v - knot) * 2.5f;
        float um = 1.0f - u;
        float u2 = u * u, u3 = u2 * u;
        const float s6 = 1.0f / 6.0f;
        float w0 = um * um * um * s6;
        float w1 = (3.0f * u3 - 6.0f * u2 + 4.0f) * s6;
        float w2 = (-3.0f * u3 + 3.0f * u2 + 3.0f * u + 1.0f) * s6;
        float w3 = u3 * s6;
        int i0 = j - 3;
        if (i0 >= 0)               bs[i0]     = w0;
        if (i0 + 1 >= 0 && i0 < 7) bs[i0 + 1] = w1;
        if (i0 + 2 >= 0 && i0 < 6) bs[i0 + 2] = w2;
        if (i0 + 3 <= 7)           bs[i0 + 3] = w3;
    }
}

// ---- pre-kernel: fp32 weights -> bf16, pre-swizzled into MFMA B-frag order ----
__global__ __launch_bounds__(256)
void cvt_swz_kernel(const float* __restrict__ ws, const float* __restrict__ wb,
                    unsigned short* __restrict__ wst, unsigned short* __restrict__ wbt) {
    int i = blockIdx.x * 256 + threadIdx.x;
    if (i < 147456) {
        int j = i & 7, l = (i >> 3) & 63, t = i >> 9;   // t 0..287
        int s = t % 144, nf = t / 144;
        int oc = nf * 32 + (l & 31);
        int k  = s * 16 + (l >> 5) * 8 + j;
        wst[i] = f2bf(ws[oc * 2304 + k]);
    } else {
        int i2 = i - 147456;
        if (i2 < 18432) {
            int j = i2 & 7, l = (i2 >> 3) & 63, t = i2 >> 9;  // t 0..35
            int s = t % 18, nf = t / 18;
            int oc = nf * 32 + (l & 31);
            int k  = s * 16 + (l >> 5) * 8 + j;
            wbt[i2] = f2bf(wb[oc * 288 + k]);
        }
    }
}

__global__ __launch_bounds__(256, 3)
void kan_mfma_kernel(const float* __restrict__ x,
                     const float* __restrict__ sc,
                     const unsigned short* __restrict__ wst,
                     const unsigned short* __restrict__ wbt,
                     float* __restrict__ out) {
    __shared__ unsigned short smem[24832];   // 49664 B -> 3 blocks/CU
    unsigned short* sb    = smem;            // [32][60][8] = 15360 ushorts
    unsigned short* patch = smem + 15360;    // [32][296]   = 9472 ushorts

    const int tid = threadIdx.x;
    const int bx  = blockIdx.x;              // 0..391
    const int b   = bx / 98;
    const int r   = bx - b * 98;
    const int ty  = r / 7;
    const int tx  = r - ty * 7;
    const int h0  = ty * 4, w0 = tx * 8;

    const int lane = tid & 63;
    const int wv   = tid >> 6;        // 0..3
    const int nf   = wv & 1;          // oc half
    const int kh2  = wv >> 1;         // K half
    const int m    = lane & 31;       // A row = pixel
    const int kg   = lane >> 5;       // k-group within k16 step
    const int py0  = m >> 3, px0 = m & 7;

    const unsigned short* bp  = wst + ((nf * 144 + kh2 * 72) * 64 + lane) * 8;
    const unsigned short* bbp = wbt + ((nf * 18  + kh2 * 9 ) * 64 + lane) * 8;

    // spline A offsets (ushort units): step s = kh2*72+g*9+u reads p = 2s+kg
    int aoff[9];
    #pragma unroll
    for (int u = 0; u < 9; ++u) {
        int t2  = 2 * u + kg;         // 0..17
        int dc  = t2 / 9;
        int tap = t2 - dc * 9;
        int kh  = tap / 3;
        int kw  = tap - kh * 3;
        aoff[u] = (dc * 60 + (py0 + kh) * 10 + (px0 + kw)) * 8;
    }

    // ---- early prefetch: spline g=0 B frags (independent of LDS) ----
    bf16x8 bufA[9], bufB[9];
    #pragma unroll
    for (int u = 0; u < 9; ++u)
        bufA[u] = *reinterpret_cast<const bf16x8*>(bp + u * 512);

    // ---- phase 1: batch 8 independent x loads, then eval + store + scatter ----
    float vv[8];
    #pragma unroll
    for (int j = 0; j < 8; ++j) {
        int i = tid + j * 256;        // 0..2047
        float val = 0.0f;
        if (i < 1920) {
            int c  = i / 60;
            int hp = i - c * 60;
            int hy = hp / 10;
            int hx = hp - hy * 10;
            int hh = h0 + hy - 1, ww = w0 + hx - 1;
            if ((unsigned)hh < 56u && (unsigned)ww < 56u)
                val = x[((b * 32 + c) * 56 + hh) * 56 + ww];
        }
        vv[j] = val;
    }
    #pragma unroll
    for (int j = 0; j < 8; ++j) {
        int i = tid + j * 256;
        if (i < 1920) {
            int c  = i / 60;
            int hp = i - c * 60;
            int hy = hp / 10;
            int hx = hp - hy * 10;
            float bs[8];
            eval_bases(vv[j], bs);
            bf16x8 pk;
            #pragma unroll
            for (int j2 = 0; j2 < 8; ++j2) pk[j2] = (short)f2bf(bs[j2]);
            *reinterpret_cast<bf16x8*>(&sb[i * 8]) = pk;
            // scatter x into patch: halo (hy,hx) -> m=(hy-kh, hx-kw), k=c*9+kh*3+kw
            unsigned short xb = f2bf(vv[j]);
            #pragma unroll
            for (int kh = 0; kh < 3; ++kh) {
                int py = hy - kh;
                if ((unsigned)py < 4u) {
                    #pragma unroll
                    for (int kw = 0; kw < 3; ++kw) {
                        int px = hx - kw;
                        if ((unsigned)px < 8u)
                            patch[(py * 8 + px) * 296 + c * 9 + kh * 3 + kw] = xb;
                    }
                }
            }
        }
    }
    __syncthreads();

    // ---- spline GEMM: 72 k16-steps, ping-pong B prefetch, dual acc chains ----
    f32x16 acc0, acc1, accB;
    #pragma unroll
    for (int i = 0; i < 16; ++i) { acc0[i] = 0.f; acc1[i] = 0.f; accB[i] = 0.f; }

    int cbase = kh2 * 7680;           // (16*kh2) channels * 480 ushorts
    for (int g = 0; g < 8; g += 2) {
        #pragma unroll
        for (int u = 0; u < 9; ++u)
            bufB[u] = *reinterpret_cast<const bf16x8*>(bp + ((g + 1) * 9 + u) * 512);
        #pragma unroll
        for (int u = 0; u < 9; ++u) {
            bf16x8 a = *reinterpret_cast<const bf16x8*>(&sb[cbase + aoff[u]]);
            if (u & 1) acc1 = MFMA32(a, bufA[u], acc1);
            else       acc0 = MFMA32(a, bufA[u], acc0);
        }
        cbase += 960;
        if (g + 2 < 8) {
            #pragma unroll
            for (int u = 0; u < 9; ++u)
                bufA[u] = *reinterpret_cast<const bf16x8*>(bp + ((g + 2) * 9 + u) * 512);
        }
        #pragma unroll
        for (int u = 0; u < 9; ++u) {
            bf16x8 a = *reinterpret_cast<const bf16x8*>(&sb[cbase + aoff[u]]);
            if (u & 1) acc1 = MFMA32(a, bufB[u], acc1);
            else       acc0 = MFMA32(a, bufB[u], acc0);
        }
        cbase += 960;
    }

    // ---- base GEMM: 9 k16-steps, prefetched B ----
    {
        #pragma unroll
        for (int s = 0; s < 9; ++s)
            bufA[s] = *reinterpret_cast<const bf16x8*>(bbp + s * 512);
        const unsigned short* ap = &patch[m * 296 + kh2 * 144 + kg * 8];
        #pragma unroll
        for (int s = 0; s < 9; ++s) {
            bf16x8 a = *reinterpret_cast<const bf16x8*>(ap + s * 16);
            accB = MFMA32(a, bufA[s], accB);
        }
    }

    // merge spline chains
    #pragma unroll
    for (int i = 0; i < 16; ++i) acc0[i] += acc1[i];

    // ---- K-split reduction: waves 2,3 -> waves 0,1 via LDS ----
    __syncthreads();
    float* red = (float*)smem;        // [2][64][36] floats = 18432 B
    if (kh2 == 1) {
        float* dst = red + (nf * 64 + lane) * 36;
        #pragma unroll
        for (int rq = 0; rq < 4; ++rq) {
            f32x4 vS, vB;
            #pragma unroll
            for (int rr = 0; rr < 4; ++rr) { vS[rr] = acc0[rq*4+rr]; vB[rr] = accB[rq*4+rr]; }
            *reinterpret_cast<f32x4*>(dst + rq * 4)      = vS;
            *reinterpret_cast<f32x4*>(dst + 16 + rq * 4) = vB;
        }
    }
    __syncthreads();

    if (kh2 == 0) {
        const float* src = red + (nf * 64 + lane) * 36;
        #pragma unroll
        for (int rq = 0; rq < 4; ++rq) {
            f32x4 vS = *reinterpret_cast<const f32x4*>(src + rq * 4);
            f32x4 vB = *reinterpret_cast<const f32x4*>(src + 16 + rq * 4);
            #pragma unroll
            for (int rr = 0; rr < 4; ++rr) { acc0[rq*4+rr] += vS[rr]; accB[rq*4+rr] += vB[rr]; }
        }
        // ---- epilogue: C/D row = (reg&3) + 4*(lane>>5); py = reg&3, pxb = 4*kg ----
        const int col = lane & 31;
        const int oc  = nf * 32 + col;
        const float scv = sc[oc];
        float* ob = out + ((b * 64 + oc) * 56 + h0) * 56 + w0 + 4 * kg;
        #pragma unroll
        for (int rq = 0; rq < 4; ++rq) {
            f32x4 res;
            #pragma unroll
            for (int rr = 0; rr < 4; ++rr) {
                float bv = accB[rq * 4 + rr];
                float si = bv / (1.0f + __expf(-bv));
                res[rr] = si + scv * acc0[rq * 4 + rr];
            }
            *reinterpret_cast<f32x4*>(ob + rq * 56) = res;
        }
    }
}

extern "C" void kernel_launch(void* const* d_in, const int* in_sizes, int n_in,
                              void* d_out, int out_size, void* d_ws, size_t ws_size,
                              hipStream_t stream) {
    const float* x  = (const float*)d_in[0];   // (4,32,56,56)
    const float* wb = (const float*)d_in[1];   // (64,32,3,3)
    const float* ws = (const float*)d_in[2];   // (64,288,8)
    const float* sc = (const float*)d_in[3];   // (64,)
    float* out = (float*)d_out;                // (4,64,56,56)

    unsigned short* wst = (unsigned short*)d_ws;   // 147456 bf16
    unsigned short* wbt = wst + 147456;            // 18432 bf16

    cvt_swz_kernel<<<648, 256, 0, stream>>>(ws, wb, wst, wbt);
    kan_mfma_kernel<<<392, 256, 0, stream>>>(x, sc, wst, wbt, out);
}